// Round 18
// baseline (740.049 us; speedup 1.0000x reference)
//
#include <hip/hip_runtime.h>
#include <cstdint>
#include <cstddef>

// ---------------------------------------------------------------------------
// QBasicBlock: qconv3x3(s2) -> inorm -> quant_a -> qconv3x3(s1) -> inorm
//            + qconv1x1(s2) -> inorm  (shortcut), output sum, NCHW f32.
// R18: R17's fragment-major direct-to-reg B + the missing prefetch slack:
//      B for period p+1 is loaded into a second register buffer at the top
//      of period p (full period of MFMA covers L2 latency; the end-of-period
//      vmcnt(0)+barrier proves it landed). Static bfrA/bfrB via period-pair
//      unroll. A path unchanged (LDS 4-ring, conflict-free swizzle).
// ---------------------------------------------------------------------------

typedef unsigned short ushort_t;
typedef __attribute__((ext_vector_type(8))) short bf16x8;
typedef __attribute__((ext_vector_type(4))) int i32x4;

// ---- problem constants ----
#define NB   32
#define C_IN 256
#define HIN  56
#define CO   512
#define OHW  784           // 28*28
#define OWD  28
#define MTOT (NB * OHW)    // 25088

#define S_X  (6.0f / 127.0f)   // fixed symmetric x-quant scale (>=6 sigma)

// ---- workspace layout (bytes) ----
constexpr size_t OFF_XH   = 0;                        // x NHWC i8
constexpr size_t OFF_A1   = OFF_XH  + 25690112;       // a1 NHWC i8
constexpr size_t OFF_H2   = OFF_A1  + 12845056;       // h2 NHWC bf16
constexpr size_t OFF_S    = OFF_H2  + 25690112;       // shortcut NHWC bf16
constexpr size_t OFF_WT1  = OFF_S   + 25690112;       // wt1 i8 frag-major [36][32768]
constexpr size_t OFF_WT2  = OFF_WT1 + 1179648;        // wt2 i8 frag-major [72][32768]
constexpr size_t OFF_WTP  = OFF_WT2 + 2359296;        // wtp i8 frag-major [4][32768]
constexpr size_t OFF_A1N  = OFF_WTP + 131072;         // per-(n,c) affine x6
constexpr size_t OFF_B1N  = OFF_A1N + 65536;
constexpr size_t OFF_A2N  = OFF_B1N + 65536;
constexpr size_t OFF_B2N  = OFF_A2N + 65536;
constexpr size_t OFF_APN  = OFF_B2N + 65536;
constexpr size_t OFF_BPN  = OFF_APN + 65536;
// ---- zeroed region (single memset): MX | ZB | CS | PSUM ----
constexpr size_t OFF_MX   = OFF_BPN + 65536;          // 3 uint absmax slots
constexpr size_t OFF_ZB   = OFF_MX  + 16;             // 2 KiB zero page
constexpr size_t OFF_CS   = OFF_ZB  + 2048;           // colsum f32 [9][512]
constexpr size_t OFF_PSUM = OFF_CS  + 18432;          // 6 x [32][512] f32
constexpr size_t ZERO_LEN = 16 + 2048 + 18432 + 393216;

// ---- helpers ----
__device__ __forceinline__ ushort_t f2bf(float f) {  // RNE f32->bf16
    unsigned u = __float_as_uint(f);
    u += 0x7FFFu + ((u >> 16) & 1u);
    return (ushort_t)(u >> 16);
}
__device__ __forceinline__ float bf2f(ushort_t u) {
    return __uint_as_float(((unsigned)u) << 16);
}

__device__ __forceinline__ void async_copy16(const void* g, const void* l) {
    auto gp = (const __attribute__((address_space(1))) unsigned int*)(uintptr_t)g;
    auto lp = (__attribute__((address_space(3))) unsigned int*)(unsigned int)(uintptr_t)l;
    __builtin_amdgcn_global_load_lds(gp, lp, 16, 0, 0);
}

// fragment-major weight address: element (kt = khw*CKT + ci/64, co, ci)
// -> kt*32768 + (co>>4)*1024 + ((co&15) | (((ci>>4)&3)<<4))*16 + (ci&15)
__device__ __forceinline__ size_t wfrag_addr(int kt, int co, int ci) {
    return (size_t)kt * 32768 + (size_t)(co >> 4) * 1024 +
           (size_t)(((co & 15) | (((ci >> 4) & 3) << 4)) * 16 + (ci & 15));
}

// ---------------------------------------------------------------------------
// 1) x NCHW f32 -> NHWC i8 (symmetric, fixed scale 6/127)
// ---------------------------------------------------------------------------
__global__ void to_nhwc_i8_k(const float* __restrict__ x, signed char* __restrict__ xh) {
    __shared__ float tile[64][33];
    const int wt0 = blockIdx.x * 32;
    const int ct0 = blockIdx.y * 64;
    const int nh  = blockIdx.z;
    const int n = nh / HIN, h = nh - n * HIN;
    {
        const int tx = threadIdx.x & 31;
        const int ty = threadIdx.x >> 5;
        const int w  = wt0 + tx;
#pragma unroll
        for (int j = 0; j < 8; ++j) {
            int cl = ty + j * 8;
            if (w < HIN)
                tile[cl][tx] = x[(((size_t)n * C_IN + ct0 + cl) * HIN + h) * HIN + w];
        }
    }
    __syncthreads();
    {
        const float inv = 127.0f / 6.0f;
        const int tc4 = threadIdx.x & 15;
        const int tw  = threadIdx.x >> 4;
#pragma unroll
        for (int j = 0; j < 2; ++j) {
            int wl = tw + j * 16;
            int w  = wt0 + wl;
            if (w < HIN) {
                unsigned pk = 0;
#pragma unroll
                for (int k = 0; k < 4; ++k) {
                    float v = tile[tc4 * 4 + k][wl];
                    float q = fminf(127.f, fmaxf(-127.f, rintf(v * inv)));
                    pk |= ((unsigned)((int)q & 0xFF)) << (8 * k);
                }
                *(unsigned*)&xh[(((size_t)n * HIN + h) * HIN + w) * C_IN + ct0 + tc4 * 4] = pk;
            }
        }
    }
}

// ---------------------------------------------------------------------------
// 2) per-tensor |w| max — 3 weight tensors in one launch (float4 reads)
// ---------------------------------------------------------------------------
__global__ void absmax3_k(const float* __restrict__ w1, int n1,
                          const float* __restrict__ w2, int n2,
                          const float* __restrict__ wp, int np,
                          unsigned* out) {
    const float4* w; int nelem;
    if (blockIdx.y == 0)      { w = (const float4*)w1; nelem = n1 >> 2; }
    else if (blockIdx.y == 1) { w = (const float4*)w2; nelem = n2 >> 2; }
    else                      { w = (const float4*)wp; nelem = np >> 2; }
    int stride = gridDim.x * blockDim.x;
    float m = 0.f;
    for (int i = blockIdx.x * blockDim.x + threadIdx.x; i < nelem; i += stride) {
        float4 v = w[i];
        m = fmaxf(m, fmaxf(fmaxf(fabsf(v.x), fabsf(v.y)),
                           fmaxf(fabsf(v.z), fabsf(v.w))));
    }
#pragma unroll
    for (int off = 32; off > 0; off >>= 1)
        m = fmaxf(m, __shfl_down(m, off));
    if ((threadIdx.x & 63) == 0) atomicMax(out + blockIdx.y, __float_as_uint(m));
}

// ---------------------------------------------------------------------------
// 3) merged weight quant (all i8, fragment-major)
// ---------------------------------------------------------------------------
__global__ void quantw_all_k(const float* __restrict__ w1,
                             const float* __restrict__ w2,
                             const float* __restrict__ wp,
                             const unsigned* __restrict__ mx,
                             signed char* __restrict__ wt1,
                             signed char* __restrict__ wt2,
                             signed char* __restrict__ wtp,
                             float* __restrict__ cs) {
    const int b = blockIdx.x;
    if (b < 4608) {            // w1 i8, CIN=256 (CKT=4)
        int idx = b * 256 + threadIdx.x;
        float scale = __uint_as_float(mx[0]) * (1.0f / 127.0f);
        float inv   = scale > 0.f ? 1.0f / scale : 0.f;
        int khw = idx / (CO * C_IN);
        int r   = idx - khw * (CO * C_IN);
        int co  = r / C_IN;
        int ci  = r - co * C_IN;
        float v  = w1[((size_t)co * C_IN + ci) * 9 + khw];
        float qv = rintf(v * inv);
        qv = fminf(127.f, fmaxf(-127.f, qv));
        wt1[wfrag_addr(khw * 4 + (ci >> 6), co, ci)] = (signed char)(int)qv;
    } else if (b < 13824) {    // w2 i8, CIN=512 (CKT=8) + colsum
        int idx = (b - 4608) * 256 + threadIdx.x;
        float scale = __uint_as_float(mx[1]) * (1.0f / 127.0f);
        float inv   = scale > 0.f ? 1.0f / scale : 0.f;
        int khw = idx / (CO * CO);
        int r   = idx - khw * (CO * CO);
        int co  = r / CO;
        int ci  = r - co * CO;
        float v  = w2[((size_t)co * CO + ci) * 9 + khw];
        float qv = rintf(v * inv);
        qv = fminf(127.f, fmaxf(-127.f, qv));
        int iq = (int)qv;
        wt2[wfrag_addr(khw * 8 + (ci >> 6), co, ci)] = (signed char)iq;
        int s = iq;
#pragma unroll
        for (int off = 32; off > 0; off >>= 1)
            s += __shfl_down(s, off);
        if ((threadIdx.x & 63) == 0) atomicAdd(&cs[khw * CO + co], (float)s);
    } else {                   // wp i8, CIN=256 (CKT=4), khw=0
        int idx = (b - 13824) * 256 + threadIdx.x;
        float scale = __uint_as_float(mx[2]) * (1.0f / 127.0f);
        float inv   = scale > 0.f ? 1.0f / scale : 0.f;
        int co  = idx / C_IN;
        int ci  = idx - co * C_IN;
        float v  = wp[(size_t)co * C_IN + ci];
        float qv = rintf(v * inv);
        qv = fminf(127.f, fmaxf(-127.f, qv));
        wtp[wfrag_addr(ci >> 6, co, ci)] = (signed char)(int)qv;
    }
}

// ---------------------------------------------------------------------------
// 4) unified INT8 implicit-GEMM conv: 256x256 tile, 196 blocks, 1024 thr
//    (16 waves, 4Mx4N, per-wave 64x64). A: LDS 4-ring + swizzle, 2 K-tiles/
//    barrier period. B: fragment-major direct->VGPR, DOUBLE-BUFFERED one
//    period ahead (bfr for p+1 loaded at top of p; end-of-period vmcnt(0)
//    + barrier guarantees it landed before the swap).
// ---------------------------------------------------------------------------
template <int CIN, int KH, int KW, int STRIDE, int PAD, int IH, int IW, bool OFFSET>
__launch_bounds__(1024, 4)
__global__ void conv_i8_t(const signed char* __restrict__ xin,
                          const signed char* __restrict__ wt,
                          const float* __restrict__ colsum,
                          const unsigned* __restrict__ mxw,
                          float sxa,
                          ushort_t* __restrict__ out,
                          const signed char* __restrict__ zbuf,
                          float* __restrict__ psum, float* __restrict__ pss) {
    constexpr int BK   = 64;
    constexpr int CKT  = CIN / BK;
    constexpr int KT   = KH * KW * CKT;
    constexpr int NPER = KT / 2;     // even for all three convs

    __shared__ alignas(16) signed char As[4 * 256 * BK];   // 64 KiB (4-ring)

    const int tid  = threadIdx.x;
    const int lane = tid & 63;
    const int wv   = tid >> 6;       // 0..15
    const int wm   = wv >> 2;        // 0..3
    const int wn   = wv & 3;         // 0..3
    const int lrow = lane & 15;
    const int lq   = lane >> 4;

    const int bid = blockIdx.x;
    const int xcd = bid & 7;
    const int j   = bid >> 3;
    const int wg  = (xcd < 4 ? xcd * 25 : 100 + (xcd - 4) * 24) + j;
    const int m0  = (wg >> 1) * 256;
    const int co0 = (wg & 1) * 256;

    // ---- A staging slot: row = tid>>2 (0..255), chunk = tid&3 (16B) ----
    const int arow = tid >> 2;
    const int ach  = tid & 3;
    int abase; unsigned amask;
    {
        int m   = m0 + arow;
        int n   = m / OHW;
        int sp  = m - n * OHW;
        int oh  = sp / OWD, ow = sp - oh * OWD;
        int ihb = oh * STRIDE - PAD, iwb = ow * STRIDE - PAD;
        int swz = (ach ^ ((arow >> 1) & 3)) * 16;   // conflict-free swizzle
        abase = (n * (IH * IW) + ihb * IW + iwb) * CIN + swz;
        unsigned mk = 0;
#pragma unroll
        for (int kh = 0; kh < KH; ++kh)
#pragma unroll
            for (int kw = 0; kw < KW; ++kw) {
                int ih = ihb + kh, iw = iwb + kw;
                if ((unsigned)ih < (unsigned)IH && (unsigned)iw < (unsigned)IW)
                    mk |= 1u << (kh * KW + kw);
            }
        amask = mk;
    }

    auto stageA = [&](int buf, int aoff, int khw) {
        const signed char* src = ((amask >> khw) & 1)
            ? xin + (abase + aoff) : zbuf;
        async_copy16(src, (const void*)&As[buf * 16384 + wv * 1024]);
    };

    // ---- B fragment base offsets (fragment-major layout) ----
    size_t bbase[4];
#pragma unroll
    for (int ni = 0; ni < 4; ++ni)
        bbase[ni] = (size_t)((co0 >> 4) + wn * 4 + ni) * 1024 + (size_t)lane * 16;

    i32x4 acc[4][4];
#pragma unroll
    for (int a = 0; a < 4; ++a)
#pragma unroll
        for (int b = 0; b < 4; ++b) acc[a][b] = {0, 0, 0, 0};

    i32x4 bfrA[2][4], bfrB[2][4];

    // A-staging coords for the next tile to stage (after tiles 0,1)
    int khw_n = 0, kw_n = 0, ck_n = 2;
    int aoff_n = 2 * BK;

    // period body: consume CUR's B, prefetch NXT's B (period p+1), stage A
    auto period = [&](int p, i32x4 (&cur)[2][4], i32x4 (&nxt)[2][4]) {
        const int t0 = 2 * p;
        if (p + 1 < NPER) {
            // prefetch B for period p+1 (tiles t0+2, t0+3): full period to land
#pragma unroll
            for (int sub = 0; sub < 2; ++sub)
#pragma unroll
                for (int ni = 0; ni < 4; ++ni)
                    nxt[sub][ni] = *(const i32x4*)(wt + (size_t)(t0 + 2 + sub) * 32768 + bbase[ni]);
            // stage A for tiles t0+2, t0+3
#pragma unroll
            for (int u = 0; u < 2; ++u) {
                const int buf = (t0 + 2 + u) & 3;
                stageA(buf, aoff_n, khw_n);
                ck_n++;
                if (ck_n == CKT) {
                    ck_n = 0; khw_n++; kw_n++;
                    if (kw_n == KW) { kw_n = 0; aoff_n += (IW - KW) * CIN + BK; }
                    else            { aoff_n += BK; }
                } else {
                    aoff_n += BK;
                }
            }
        }
        __builtin_amdgcn_sched_barrier(0);

#pragma unroll
        for (int sub = 0; sub < 2; ++sub) {
            const signed char* Acur = &As[((t0 + sub) & 3) * 16384];
            i32x4 af[4];
#pragma unroll
            for (int mi = 0; mi < 4; ++mi) {
                const int row = wm * 64 + mi * 16 + lrow;
                af[mi] = *(const i32x4*)&Acur[row * BK + ((lq ^ ((row >> 1) & 3)) * 16)];
            }
#pragma unroll
            for (int mi = 0; mi < 4; ++mi)
#pragma unroll
                for (int ni = 0; ni < 4; ++ni)
                    acc[mi][ni] = __builtin_amdgcn_mfma_i32_16x16x64_i8(
                        af[mi], cur[sub][ni], acc[mi][ni], 0, 0, 0);
        }

        asm volatile("s_waitcnt vmcnt(0)" ::: "memory");
        __builtin_amdgcn_sched_barrier(0);
        __builtin_amdgcn_s_barrier();
    };

    // ---- prologue: B for period 0 + stage A tiles 0,1 ----
#pragma unroll
    for (int sub = 0; sub < 2; ++sub)
#pragma unroll
        for (int ni = 0; ni < 4; ++ni)
            bfrA[sub][ni] = *(const i32x4*)(wt + (size_t)sub * 32768 + bbase[ni]);
    stageA(0, 0, 0);
    stageA(1, BK, 0);
    asm volatile("s_waitcnt vmcnt(0)" ::: "memory");
    __builtin_amdgcn_s_barrier();

#pragma unroll 1
    for (int pp = 0; pp < NPER / 2; ++pp) {
        period(2 * pp,     bfrA, bfrB);
        period(2 * pp + 1, bfrB, bfrA);
    }

    // ---- epilogue: dequant (+fixup) + bf16 store + fused stats ----
    const int mb = m0 + wm * 64 + lq * 4;
    const int cb = co0 + wn * 64 + lrow;
    const float sw = __uint_as_float(*mxw) * (1.0f / 127.0f);
    float sc, c128 = 0.f;
    if constexpr (OFFSET) { sc = sw * (1.0f / 255.0f); c128 = 128.0f * sc; }
    else                  { sc = sxa * sw; }

    float Sall[4], Sr0[4], Sr2[4], Sc0[4], Sc2[4], K0[4], K2[4], K6[4], K8[4];
    if constexpr (OFFSET) {
#pragma unroll
        for (int ni = 0; ni < 4; ++ni) {
            float cs9[9];
#pragma unroll
            for (int k = 0; k < 9; ++k) cs9[k] = colsum[k * CO + cb + ni * 16];
            Sall[ni] = cs9[0]+cs9[1]+cs9[2]+cs9[3]+cs9[4]+cs9[5]+cs9[6]+cs9[7]+cs9[8];
            Sr0[ni] = cs9[0]+cs9[1]+cs9[2];  Sr2[ni] = cs9[6]+cs9[7]+cs9[8];
            Sc0[ni] = cs9[0]+cs9[3]+cs9[6];  Sc2[ni] = cs9[2]+cs9[5]+cs9[8];
            K0[ni] = cs9[0]; K2[ni] = cs9[2]; K6[ni] = cs9[6]; K8[ni] = cs9[8];
        }
    }

    const int n0 = m0 / OHW;
    const int mS = (n0 + 1) * OHW;
    float sv[2][4], qvv[2][4];
#pragma unroll
    for (int g = 0; g < 2; ++g)
#pragma unroll
        for (int ni = 0; ni < 4; ++ni) { sv[g][ni] = 0.f; qvv[g][ni] = 0.f; }

#pragma unroll
    for (int mi = 0; mi < 4; ++mi)
#pragma unroll
        for (int r = 0; r < 4; ++r) {
            const int m  = mb + mi * 16 + r;
            const int n  = m / OHW;
            const int sp = m - n * OHW;
            const int oh = sp / OWD, ow = sp - oh * OWD;
            const int g  = (m >= mS) ? 1 : 0;
#pragma unroll
            for (int ni = 0; ni < 4; ++ni) {
                float val;
                if constexpr (OFFSET) {
                    float T = Sall[ni];
                    if (oh == 0)       T -= Sr0[ni];
                    if (oh == OWD - 1) T -= Sr2[ni];
                    if (ow == 0)       T -= Sc0[ni];
                    if (ow == OWD - 1) T -= Sc2[ni];
                    if (oh == 0 && ow == 0)             T += K0[ni];
                    if (oh == 0 && ow == OWD - 1)       T += K2[ni];
                    if (oh == OWD - 1 && ow == 0)       T += K6[ni];
                    if (oh == OWD - 1 && ow == OWD - 1) T += K8[ni];
                    val = sc * (float)acc[mi][ni][r] + c128 * T;
                } else {
                    val = sc * (float)acc[mi][ni][r];
                }
                out[(size_t)m * CO + (cb + ni * 16)] = f2bf(val);
                sv[g][ni] += val; qvv[g][ni] += val * val;
            }
        }
#pragma unroll
    for (int d = 16; d <= 32; d <<= 1)
#pragma unroll
        for (int g = 0; g < 2; ++g)
#pragma unroll
            for (int ni = 0; ni < 4; ++ni) {
                sv[g][ni]  += __shfl_xor(sv[g][ni], d);
                qvv[g][ni] += __shfl_xor(qvv[g][ni], d);
            }
    if (lq == 0) {
        const bool split = (mS < m0 + 256);
#pragma unroll
        for (int ni = 0; ni < 4; ++ni) {
            atomicAdd(&psum[n0 * CO + cb + ni * 16], sv[0][ni]);
            atomicAdd(&pss [n0 * CO + cb + ni * 16], qvv[0][ni]);
            if (split) {
                atomicAdd(&psum[(n0 + 1) * CO + cb + ni * 16], sv[1][ni]);
                atomicAdd(&pss [(n0 + 1) * CO + cb + ni * 16], qvv[1][ni]);
            }
        }
    }
}

// ---------------------------------------------------------------------------
// 5) stats finalize x3 in one launch
// ---------------------------------------------------------------------------
__global__ void statsf3_k(const float* __restrict__ ps0, const float* __restrict__ qs0,
                          const float* __restrict__ g0, const float* __restrict__ bb0,
                          float* __restrict__ ao0, float* __restrict__ bo0,
                          const float* __restrict__ ps1, const float* __restrict__ qs1,
                          const float* __restrict__ g1, const float* __restrict__ bb1,
                          float* __restrict__ ao1, float* __restrict__ bo1,
                          const float* __restrict__ ps2, const float* __restrict__ qs2,
                          const float* __restrict__ g2, const float* __restrict__ bb2,
                          float* __restrict__ ao2, float* __restrict__ bo2) {
    const float *ps, *qs, *g, *bb; float *ao, *bo;
    if (blockIdx.y == 0)      { ps = ps0; qs = qs0; g = g0; bb = bb0; ao = ao0; bo = bo0; }
    else if (blockIdx.y == 1) { ps = ps1; qs = qs1; g = g1; bb = bb1; ao = ao1; bo = bo1; }
    else                      { ps = ps2; qs = qs2; g = g2; bb = bb2; ao = ao2; bo = bo2; }
    int idx = blockIdx.x * 256 + threadIdx.x;
    int c = idx & 511;
    float s  = ps[idx];
    float ss = qs[idx];
    float mean = s * (1.0f / 784.0f);
    float var  = ss * (1.0f / 784.0f) - mean * mean;
    float rstd = rsqrtf(var + 1e-5f);
    float a = rstd * g[c];
    ao[idx] = a;
    bo[idx] = bb[c] - mean * a;
}

// ---------------------------------------------------------------------------
// 6) apply norm1 + quant_a: bf16 h1 -> i8 (k-128) a1
// ---------------------------------------------------------------------------
__global__ void norm_quant_i8_k(const ushort_t* __restrict__ h, const float* __restrict__ a_,
                                const float* __restrict__ b_, signed char* __restrict__ o) {
    int idx = blockIdx.x * 256 + threadIdx.x;   // over M*512/8
    int row = idx >> 6;
    int c0  = (idx & 63) * 8;
    int n   = row / OHW;
    bf16x8 v = ((const bf16x8*)h)[idx];
    const float* ap = a_ + n * CO + c0;
    const float* bp = b_ + n * CO + c0;
    unsigned lo = 0, hi = 0;
#pragma unroll
    for (int k = 0; k < 8; ++k) {
        float f = bf2f((ushort_t)v[k]) * ap[k] + bp[k];
        float kq = rintf(fminf(fmaxf(f, 0.f), 1.f) * 255.f);
        int s8 = (int)kq - 128;
        unsigned b = (unsigned)(s8 & 0xFF);
        if (k < 4) lo |= b << (8 * k);
        else       hi |= b << (8 * (k - 4));
    }
    ((uint2*)o)[idx] = make_uint2(lo, hi);
}

// ---------------------------------------------------------------------------
// 7) final: out NCHW f32 = norm2(h2) + normp(s), bf16 in, LDS transpose
// ---------------------------------------------------------------------------
__global__ void final_k(const ushort_t* __restrict__ h2, const ushort_t* __restrict__ s,
                        const float* __restrict__ a2, const float* __restrict__ b2,
                        const float* __restrict__ ap_, const float* __restrict__ bp_,
                        float* __restrict__ out) {
    __shared__ float tile[64][33];
    const int sp0 = blockIdx.x * 32;
    const int c0  = blockIdx.y * 64;
    const int n   = blockIdx.z;
    const int tx  = threadIdx.x & 31;
    const int ty  = threadIdx.x >> 5;
#pragma unroll
    for (int j = 0; j < 4; ++j) {
        int spl = ty + j * 8;
        int sp  = sp0 + spl;
        if (sp < OHW) {
            int c = c0 + tx * 2;
            size_t ix = ((size_t)n * OHW + sp) * CO + c;
            int ci = n * CO + c;
            ushort2 vh = *(const ushort2*)&h2[ix];
            ushort2 vs = *(const ushort2*)&s[ix];
            tile[tx * 2][spl] =
                bf2f(vh.x) * a2[ci] + b2[ci] + bf2f(vs.x) * ap_[ci] + bp_[ci];
            tile[tx * 2 + 1][spl] =
                bf2f(vh.y) * a2[ci + 1] + b2[ci + 1] + bf2f(vs.y) * ap_[ci + 1] + bp_[ci + 1];
        }
    }
    __syncthreads();
    const int sp = sp0 + tx;
#pragma unroll
    for (int j = 0; j < 8; ++j) {
        int cl = ty + j * 8;
        if (sp < OHW)
            out[((size_t)n * CO + c0 + cl) * OHW + sp] = tile[cl][tx];
    }
}

// ---------------------------------------------------------------------------
extern "C" void kernel_launch(void* const* d_in, const int* in_sizes, int n_in,
                              void* d_out, int out_size, void* d_ws, size_t ws_size,
                              hipStream_t stream) {
    const float* x  = (const float*)d_in[0];
    const float* w1 = (const float*)d_in[1];
    const float* g1 = (const float*)d_in[2];
    const float* b1 = (const float*)d_in[3];
    const float* w2 = (const float*)d_in[4];
    const float* g2 = (const float*)d_in[5];
    const float* b2 = (const float*)d_in[6];
    const float* wp = (const float*)d_in[7];
    const float* gp = (const float*)d_in[8];
    const float* bp = (const float*)d_in[9];
    float* out = (float*)d_out;
    char* ws = (char*)d_ws;

    signed char* xh    = (signed char*)(ws + OFF_XH);
    signed char* a1    = (signed char*)(ws + OFF_A1);
    ushort_t*    h2    = (ushort_t*)(ws + OFF_H2);
    ushort_t*    sbuf  = (ushort_t*)(ws + OFF_S);
    signed char* wt1i  = (signed char*)(ws + OFF_WT1);
    signed char* wt2i  = (signed char*)(ws + OFF_WT2);
    signed char* wtpi  = (signed char*)(ws + OFF_WTP);
    float*    a1n  = (float*)(ws + OFF_A1N);
    float*    b1n  = (float*)(ws + OFF_B1N);
    float*    a2n  = (float*)(ws + OFF_A2N);
    float*    b2n  = (float*)(ws + OFF_B2N);
    float*    apn  = (float*)(ws + OFF_APN);
    float*    bpn  = (float*)(ws + OFF_BPN);
    unsigned* mx   = (unsigned*)(ws + OFF_MX);
    signed char* zb = (signed char*)(ws + OFF_ZB);
    float*    cs   = (float*)(ws + OFF_CS);
    float*    psum1 = (float*)(ws + OFF_PSUM);
    float*    pss1  = (float*)(ws + OFF_PSUM + 65536);
    float*    psum2 = (float*)(ws + OFF_PSUM + 131072);
    float*    pss2  = (float*)(ws + OFF_PSUM + 196608);
    float*    psump = (float*)(ws + OFF_PSUM + 262144);
    float*    pssp  = (float*)(ws + OFF_PSUM + 327680);
    ushort_t* h1   = (ushort_t*)out;   // d_out doubles as conv1 bf16 scratch

    // single memset: absmax + zero page + colsum + 6 stat buffers
    hipMemsetAsync(ws + OFF_MX, 0, ZERO_LEN, stream);

    to_nhwc_i8_k<<<dim3(2, 4, NB * HIN), 256, 0, stream>>>(x, xh);
    absmax3_k<<<dim3(512, 3), 256, 0, stream>>>(w1, CO * C_IN * 9,
                                                w2, CO * CO * 9,
                                                wp, C_IN * CO, mx);
    quantw_all_k<<<dim3(14336), 256, 0, stream>>>(w1, w2, wp, mx,
                                                  wt1i, wt2i, wtpi, cs);

    // conv1 (i8 symmetric, 3x3 s2, 256->512) -> h1 bf16 (in d_out) + stats1
    conv_i8_t<C_IN, 3, 3, 2, 1, HIN, HIN, false>
        <<<dim3(196), 1024, 0, stream>>>(xh, wt1i, cs, mx + 0, S_X, h1, zb,
                                         psum1, pss1);
    statsf3_k<<<dim3(64, 1), 256, 0, stream>>>(psum1, pss1, g1, b1, a1n, b1n,
                                               psum1, pss1, g1, b1, a1n, b1n,
                                               psum1, pss1, g1, b1, a1n, b1n);
    norm_quant_i8_k<<<dim3(MTOT * CO / 8 / 256), 256, 0, stream>>>(h1, a1n, b1n, a1);

    // conv2 (i8 offset path, 3x3 s1, 512->512) -> h2 + stats2
    conv_i8_t<CO, 3, 3, 1, 1, 28, 28, true>
        <<<dim3(196), 1024, 0, stream>>>(a1, wt2i, cs, mx + 1, 1.0f, h2, zb,
                                         psum2, pss2);
    // shortcut conv (i8 symmetric, 1x1 s2, 256->512) -> s + statsp
    conv_i8_t<C_IN, 1, 1, 2, 0, HIN, HIN, false>
        <<<dim3(196), 1024, 0, stream>>>(xh, wtpi, cs, mx + 2, S_X, sbuf, zb,
                                         psump, pssp);

    statsf3_k<<<dim3(64, 2), 256, 0, stream>>>(psum2, pss2, g2, b2, a2n, b2n,
                                               psump, pssp, gp, bp, apn, bpn,
                                               psum2, pss2, g2, b2, a2n, b2n);

    final_k<<<dim3(25, 8, NB), 256, 0, stream>>>(h2, sbuf, a2n, b2n, apn, bpn, out);
}

// Round 19
// 277.689 us; speedup vs baseline: 2.6650x; 2.6650x over previous
//
#include <hip/hip_runtime.h>
#include <cstdint>
#include <cstddef>

// ---------------------------------------------------------------------------
// QBasicBlock: qconv3x3(s2) -> inorm -> quant_a -> qconv3x3(s1) -> inorm
//            + qconv1x1(s2) -> inorm  (shortcut), output sum, NCHW f32.
// R19: revert to R16 verbatim (best measured: 277.1 us). R17/R18's
//      B-direct-to-register line is dead (uncoalesced / unhidden latency /
//      lambda-induced scratch spill). All convs on the int8 MFMA template:
//      LDS-staged A+B 4-ring, 16 waves, 2 K-tiles/barrier, conflict-free
//      swizzle; x symmetric i8 (6/127); conv2 offset path with colsum fixup.
// ---------------------------------------------------------------------------

typedef unsigned short ushort_t;
typedef __attribute__((ext_vector_type(8))) short bf16x8;
typedef __attribute__((ext_vector_type(4))) int i32x4;

// ---- problem constants ----
#define NB   32
#define C_IN 256
#define HIN  56
#define CO   512
#define OHW  784           // 28*28
#define OWD  28
#define MTOT (NB * OHW)    // 25088

#define S_X  (6.0f / 127.0f)   // fixed symmetric x-quant scale (>=6 sigma)

// ---- workspace layout (bytes) ----
constexpr size_t OFF_XH   = 0;                        // x NHWC i8
constexpr size_t OFF_A1   = OFF_XH  + 25690112;       // a1 NHWC i8
constexpr size_t OFF_H2   = OFF_A1  + 12845056;       // h2 NHWC bf16
constexpr size_t OFF_S    = OFF_H2  + 25690112;       // shortcut NHWC bf16
constexpr size_t OFF_WT1  = OFF_S   + 25690112;       // wt1 i8 [9][512][256]
constexpr size_t OFF_WT2  = OFF_WT1 + 1179648;        // wt2 i8 [9][512][512]
constexpr size_t OFF_WTP  = OFF_WT2 + 2359296;        // wtp i8 [1][512][256]
constexpr size_t OFF_A1N  = OFF_WTP + 131072;         // per-(n,c) affine x6
constexpr size_t OFF_B1N  = OFF_A1N + 65536;
constexpr size_t OFF_A2N  = OFF_B1N + 65536;
constexpr size_t OFF_B2N  = OFF_A2N + 65536;
constexpr size_t OFF_APN  = OFF_B2N + 65536;
constexpr size_t OFF_BPN  = OFF_APN + 65536;
// ---- zeroed region (single memset): MX | ZB | CS | PSUM ----
constexpr size_t OFF_MX   = OFF_BPN + 65536;          // 3 uint absmax slots
constexpr size_t OFF_ZB   = OFF_MX  + 16;             // 2 KiB zero page
constexpr size_t OFF_CS   = OFF_ZB  + 2048;           // colsum f32 [9][512]
constexpr size_t OFF_PSUM = OFF_CS  + 18432;          // 6 x [32][512] f32
constexpr size_t ZERO_LEN = 16 + 2048 + 18432 + 393216;

// ---- helpers ----
__device__ __forceinline__ ushort_t f2bf(float f) {  // RNE f32->bf16
    unsigned u = __float_as_uint(f);
    u += 0x7FFFu + ((u >> 16) & 1u);
    return (ushort_t)(u >> 16);
}
__device__ __forceinline__ float bf2f(ushort_t u) {
    return __uint_as_float(((unsigned)u) << 16);
}

__device__ __forceinline__ void async_copy16(const void* g, const void* l) {
    auto gp = (const __attribute__((address_space(1))) unsigned int*)(uintptr_t)g;
    auto lp = (__attribute__((address_space(3))) unsigned int*)(unsigned int)(uintptr_t)l;
    __builtin_amdgcn_global_load_lds(gp, lp, 16, 0, 0);
}

// ---------------------------------------------------------------------------
// 1) x NCHW f32 -> NHWC i8 (symmetric, fixed scale 6/127)
// ---------------------------------------------------------------------------
__global__ void to_nhwc_i8_k(const float* __restrict__ x, signed char* __restrict__ xh) {
    __shared__ float tile[64][33];
    const int wt0 = blockIdx.x * 32;
    const int ct0 = blockIdx.y * 64;
    const int nh  = blockIdx.z;
    const int n = nh / HIN, h = nh - n * HIN;
    {
        const int tx = threadIdx.x & 31;
        const int ty = threadIdx.x >> 5;
        const int w  = wt0 + tx;
#pragma unroll
        for (int j = 0; j < 8; ++j) {
            int cl = ty + j * 8;
            if (w < HIN)
                tile[cl][tx] = x[(((size_t)n * C_IN + ct0 + cl) * HIN + h) * HIN + w];
        }
    }
    __syncthreads();
    {
        const float inv = 127.0f / 6.0f;
        const int tc4 = threadIdx.x & 15;   // 16 groups of 4 channels
        const int tw  = threadIdx.x >> 4;   // 16 w slots
#pragma unroll
        for (int j = 0; j < 2; ++j) {
            int wl = tw + j * 16;
            int w  = wt0 + wl;
            if (w < HIN) {
                unsigned pk = 0;
#pragma unroll
                for (int k = 0; k < 4; ++k) {
                    float v = tile[tc4 * 4 + k][wl];
                    float q = fminf(127.f, fmaxf(-127.f, rintf(v * inv)));
                    pk |= ((unsigned)((int)q & 0xFF)) << (8 * k);
                }
                *(unsigned*)&xh[(((size_t)n * HIN + h) * HIN + w) * C_IN + ct0 + tc4 * 4] = pk;
            }
        }
    }
}

// ---------------------------------------------------------------------------
// 2) per-tensor |w| max — 3 weight tensors in one launch (float4 reads)
// ---------------------------------------------------------------------------
__global__ void absmax3_k(const float* __restrict__ w1, int n1,
                          const float* __restrict__ w2, int n2,
                          const float* __restrict__ wp, int np,
                          unsigned* out) {
    const float4* w; int nelem;
    if (blockIdx.y == 0)      { w = (const float4*)w1; nelem = n1 >> 2; }
    else if (blockIdx.y == 1) { w = (const float4*)w2; nelem = n2 >> 2; }
    else                      { w = (const float4*)wp; nelem = np >> 2; }
    int stride = gridDim.x * blockDim.x;
    float m = 0.f;
    for (int i = blockIdx.x * blockDim.x + threadIdx.x; i < nelem; i += stride) {
        float4 v = w[i];
        m = fmaxf(m, fmaxf(fmaxf(fabsf(v.x), fabsf(v.y)),
                           fmaxf(fabsf(v.z), fabsf(v.w))));
    }
#pragma unroll
    for (int off = 32; off > 0; off >>= 1)
        m = fmaxf(m, __shfl_down(m, off));
    if ((threadIdx.x & 63) == 0) atomicMax(out + blockIdx.y, __float_as_uint(m));
}

// ---------------------------------------------------------------------------
// 3) merged weight quant (all i8): [0,4608) wt1, [4608,13824) wt2 (+colsum),
//    [13824,14336) wtp.
// ---------------------------------------------------------------------------
__global__ void quantw_all_k(const float* __restrict__ w1,
                             const float* __restrict__ w2,
                             const float* __restrict__ wp,
                             const unsigned* __restrict__ mx,
                             signed char* __restrict__ wt1,
                             signed char* __restrict__ wt2,
                             signed char* __restrict__ wtp,
                             float* __restrict__ cs) {
    const int b = blockIdx.x;
    if (b < 4608) {            // w1 i8 [9][512][256]
        int idx = b * 256 + threadIdx.x;
        float scale = __uint_as_float(mx[0]) * (1.0f / 127.0f);
        float inv   = scale > 0.f ? 1.0f / scale : 0.f;
        int khw = idx / (CO * C_IN);
        int r   = idx - khw * (CO * C_IN);
        int co  = r / C_IN;
        int ci  = r - co * C_IN;
        float v  = w1[((size_t)co * C_IN + ci) * 9 + khw];
        float qv = rintf(v * inv);
        qv = fminf(127.f, fmaxf(-127.f, qv));
        wt1[idx] = (signed char)(int)qv;
    } else if (b < 13824) {    // w2 i8 [9][512][512] + colsum
        int idx = (b - 4608) * 256 + threadIdx.x;
        float scale = __uint_as_float(mx[1]) * (1.0f / 127.0f);
        float inv   = scale > 0.f ? 1.0f / scale : 0.f;
        int khw = idx / (CO * CO);
        int r   = idx - khw * (CO * CO);
        int co  = r / CO;
        int ci  = r - co * CO;
        float v  = w2[((size_t)co * CO + ci) * 9 + khw];
        float qv = rintf(v * inv);
        qv = fminf(127.f, fmaxf(-127.f, qv));
        int iq = (int)qv;
        wt2[idx] = (signed char)iq;
        int s = iq;
#pragma unroll
        for (int off = 32; off > 0; off >>= 1)
            s += __shfl_down(s, off);
        if ((threadIdx.x & 63) == 0) atomicAdd(&cs[khw * CO + co], (float)s);
    } else {                   // wp i8 [512][256]
        int idx = (b - 13824) * 256 + threadIdx.x;
        float scale = __uint_as_float(mx[2]) * (1.0f / 127.0f);
        float inv   = scale > 0.f ? 1.0f / scale : 0.f;
        int co  = idx / C_IN;
        int ci  = idx - co * C_IN;
        float v  = wp[(size_t)co * C_IN + ci];
        float qv = rintf(v * inv);
        qv = fminf(127.f, fmaxf(-127.f, qv));
        wtp[idx] = (signed char)(int)qv;
    }
}

// ---------------------------------------------------------------------------
// 4) unified INT8 implicit-GEMM conv (R15 structure): 256x256 tile, 196
//    blocks, 1024 threads (16 waves, 4Mx4N, per-wave 64x64). 2 K-tiles per
//    barrier period, 4-ring LDS. Conflict-free swizzle lq ^ ((row>>1)&3).
//    OFFSET=true : A = (k-128) i8 -> val = sc*dot + 128*sc*T (colsum fixup)
//    OFFSET=false: symmetric i8  -> val = sxa*sw*dot (no correction)
// ---------------------------------------------------------------------------
template <int CIN, int KH, int KW, int STRIDE, int PAD, int IH, int IW, bool OFFSET>
__launch_bounds__(1024, 4)
__global__ void conv_i8_t(const signed char* __restrict__ xin,
                          const signed char* __restrict__ wt,
                          const float* __restrict__ colsum,
                          const unsigned* __restrict__ mxw,
                          float sxa,
                          ushort_t* __restrict__ out,
                          const signed char* __restrict__ zbuf,
                          float* __restrict__ psum, float* __restrict__ pss) {
    constexpr int BK   = 64;
    constexpr int CKT  = CIN / BK;
    constexpr int KT   = KH * KW * CKT;
    constexpr int NPER = KT / 2;

    __shared__ alignas(16) signed char As[4 * 256 * BK];   // 64 KiB (4-ring)
    __shared__ alignas(16) signed char Bs[4 * 256 * BK];   // 64 KiB (4-ring)

    const int tid  = threadIdx.x;
    const int lane = tid & 63;
    const int wv   = tid >> 6;       // 0..15
    const int wm   = wv >> 2;        // 0..3
    const int wn   = wv & 3;         // 0..3
    const int lrow = lane & 15;
    const int lq   = lane >> 4;

    const int bid = blockIdx.x;
    const int xcd = bid & 7;
    const int j   = bid >> 3;
    const int wg  = (xcd < 4 ? xcd * 25 : 100 + (xcd - 4) * 24) + j;
    const int m0  = (wg >> 1) * 256;
    const int co0 = (wg & 1) * 256;

    // staging slot: row = tid>>2 (0..255), chunk = tid&3 (16B)
    const int arow = tid >> 2;
    const int ach  = tid & 3;
    int abase; unsigned amask; int bco;
    {
        int m   = m0 + arow;
        int n   = m / OHW;
        int sp  = m - n * OHW;
        int oh  = sp / OWD, ow = sp - oh * OWD;
        int ihb = oh * STRIDE - PAD, iwb = ow * STRIDE - PAD;
        int swz = (ach ^ ((arow >> 1) & 3)) * 16;   // conflict-free swizzle
        abase = (n * (IH * IW) + ihb * IW + iwb) * CIN + swz;
        unsigned mk = 0;
#pragma unroll
        for (int kh = 0; kh < KH; ++kh)
#pragma unroll
            for (int kw = 0; kw < KW; ++kw) {
                int ih = ihb + kh, iw = iwb + kw;
                if ((unsigned)ih < (unsigned)IH && (unsigned)iw < (unsigned)IW)
                    mk |= 1u << (kh * KW + kw);
            }
        amask = mk;
        bco = (co0 + arow) * CIN + swz;
    }

    auto stageA = [&](int buf, int aoff, int khw) {
        const signed char* src = ((amask >> khw) & 1)
            ? xin + (abase + aoff) : zbuf;
        async_copy16(src, (const void*)&As[buf * 16384 + wv * 1024]);
    };
    auto stageB = [&](int buf, int boff) {
        async_copy16(wt + (boff + bco), (const void*)&Bs[buf * 16384 + wv * 1024]);
    };

    i32x4 acc[4][4];
#pragma unroll
    for (int a = 0; a < 4; ++a)
#pragma unroll
        for (int b = 0; b < 4; ++b) acc[a][b] = {0, 0, 0, 0};

    // ---- prologue: tiles 0,1 -> bufs 0,1 (khw=0; ck=0,1) ----
    stageB(0, 0);  stageA(0, 0, 0);
    stageB(1, BK); stageA(1, BK, 0);
    asm volatile("s_waitcnt vmcnt(0)" ::: "memory");
    __builtin_amdgcn_s_barrier();

    int khw_n = 0, kw_n = 0, ck_n = 2;
    int aoff_n = 2 * BK;
    int boff_n = 2 * BK;

#pragma unroll 1
    for (int p = 0; p < NPER; ++p) {
        const int t0 = 2 * p;
        if (p + 1 < NPER) {
#pragma unroll
            for (int u = 0; u < 2; ++u) {
                const int buf = (t0 + 2 + u) & 3;
                stageB(buf, boff_n);
                stageA(buf, aoff_n, khw_n);
                ck_n++;
                if (ck_n == CKT) {
                    ck_n = 0; khw_n++; kw_n++;
                    if (kw_n == KW) { kw_n = 0; aoff_n += (IW - KW) * CIN + BK; }
                    else            { aoff_n += BK; }
                    boff_n += (CO - 1) * CIN + BK;
                } else {
                    aoff_n += BK; boff_n += BK;
                }
            }
        }
        __builtin_amdgcn_sched_barrier(0);

#pragma unroll
        for (int sub = 0; sub < 2; ++sub) {
            const signed char* Acur = &As[((t0 + sub) & 3) * 16384];
            const signed char* Bcur = &Bs[((t0 + sub) & 3) * 16384];
            i32x4 af[4], bfr[4];
#pragma unroll
            for (int mi = 0; mi < 4; ++mi) {
                const int row = wm * 64 + mi * 16 + lrow;
                af[mi] = *(const i32x4*)&Acur[row * BK + ((lq ^ ((row >> 1) & 3)) * 16)];
            }
#pragma unroll
            for (int ni = 0; ni < 4; ++ni) {
                const int row = wn * 64 + ni * 16 + lrow;
                bfr[ni] = *(const i32x4*)&Bcur[row * BK + ((lq ^ ((row >> 1) & 3)) * 16)];
            }
#pragma unroll
            for (int mi = 0; mi < 4; ++mi)
#pragma unroll
                for (int ni = 0; ni < 4; ++ni)
                    acc[mi][ni] = __builtin_amdgcn_mfma_i32_16x16x64_i8(
                        af[mi], bfr[ni], acc[mi][ni], 0, 0, 0);
        }

        asm volatile("s_waitcnt vmcnt(0)" ::: "memory");
        __builtin_amdgcn_sched_barrier(0);
        __builtin_amdgcn_s_barrier();
    }

    // ---- epilogue: dequant (+fixup) + bf16 store + fused stats ----
    const int mb = m0 + wm * 64 + lq * 4;
    const int cb = co0 + wn * 64 + lrow;
    const float sw = __uint_as_float(*mxw) * (1.0f / 127.0f);
    float sc, c128 = 0.f;
    if constexpr (OFFSET) { sc = sw * (1.0f / 255.0f); c128 = 128.0f * sc; }
    else                  { sc = sxa * sw; }

    float Sall[4], Sr0[4], Sr2[4], Sc0[4], Sc2[4], K0[4], K2[4], K6[4], K8[4];
    if constexpr (OFFSET) {
#pragma unroll
        for (int ni = 0; ni < 4; ++ni) {
            float cs9[9];
#pragma unroll
            for (int k = 0; k < 9; ++k) cs9[k] = colsum[k * CO + cb + ni * 16];
            Sall[ni] = cs9[0]+cs9[1]+cs9[2]+cs9[3]+cs9[4]+cs9[5]+cs9[6]+cs9[7]+cs9[8];
            Sr0[ni] = cs9[0]+cs9[1]+cs9[2];  Sr2[ni] = cs9[6]+cs9[7]+cs9[8];
            Sc0[ni] = cs9[0]+cs9[3]+cs9[6];  Sc2[ni] = cs9[2]+cs9[5]+cs9[8];
            K0[ni] = cs9[0]; K2[ni] = cs9[2]; K6[ni] = cs9[6]; K8[ni] = cs9[8];
        }
    }

    const int n0 = m0 / OHW;
    const int mS = (n0 + 1) * OHW;
    float sv[2][4], qvv[2][4];
#pragma unroll
    for (int g = 0; g < 2; ++g)
#pragma unroll
        for (int ni = 0; ni < 4; ++ni) { sv[g][ni] = 0.f; qvv[g][ni] = 0.f; }

#pragma unroll
    for (int mi = 0; mi < 4; ++mi)
#pragma unroll
        for (int r = 0; r < 4; ++r) {
            const int m  = mb + mi * 16 + r;
            const int n  = m / OHW;
            const int sp = m - n * OHW;
            const int oh = sp / OWD, ow = sp - oh * OWD;
            const int g  = (m >= mS) ? 1 : 0;
#pragma unroll
            for (int ni = 0; ni < 4; ++ni) {
                float val;
                if constexpr (OFFSET) {
                    float T = Sall[ni];
                    if (oh == 0)       T -= Sr0[ni];
                    if (oh == OWD - 1) T -= Sr2[ni];
                    if (ow == 0)       T -= Sc0[ni];
                    if (ow == OWD - 1) T -= Sc2[ni];
                    if (oh == 0 && ow == 0)             T += K0[ni];
                    if (oh == 0 && ow == OWD - 1)       T += K2[ni];
                    if (oh == OWD - 1 && ow == 0)       T += K6[ni];
                    if (oh == OWD - 1 && ow == OWD - 1) T += K8[ni];
                    val = sc * (float)acc[mi][ni][r] + c128 * T;
                } else {
                    val = sc * (float)acc[mi][ni][r];
                }
                out[(size_t)m * CO + (cb + ni * 16)] = f2bf(val);
                sv[g][ni] += val; qvv[g][ni] += val * val;
            }
        }
#pragma unroll
    for (int d = 16; d <= 32; d <<= 1)
#pragma unroll
        for (int g = 0; g < 2; ++g)
#pragma unroll
            for (int ni = 0; ni < 4; ++ni) {
                sv[g][ni]  += __shfl_xor(sv[g][ni], d);
                qvv[g][ni] += __shfl_xor(qvv[g][ni], d);
            }
    if (lq == 0) {
        const bool split = (mS < m0 + 256);
#pragma unroll
        for (int ni = 0; ni < 4; ++ni) {
            atomicAdd(&psum[n0 * CO + cb + ni * 16], sv[0][ni]);
            atomicAdd(&pss [n0 * CO + cb + ni * 16], qvv[0][ni]);
            if (split) {
                atomicAdd(&psum[(n0 + 1) * CO + cb + ni * 16], sv[1][ni]);
                atomicAdd(&pss [(n0 + 1) * CO + cb + ni * 16], qvv[1][ni]);
            }
        }
    }
}

// ---------------------------------------------------------------------------
// 5) stats finalize x3 in one launch
// ---------------------------------------------------------------------------
__global__ void statsf3_k(const float* __restrict__ ps0, const float* __restrict__ qs0,
                          const float* __restrict__ g0, const float* __restrict__ bb0,
                          float* __restrict__ ao0, float* __restrict__ bo0,
                          const float* __restrict__ ps1, const float* __restrict__ qs1,
                          const float* __restrict__ g1, const float* __restrict__ bb1,
                          float* __restrict__ ao1, float* __restrict__ bo1,
                          const float* __restrict__ ps2, const float* __restrict__ qs2,
                          const float* __restrict__ g2, const float* __restrict__ bb2,
                          float* __restrict__ ao2, float* __restrict__ bo2) {
    const float *ps, *qs, *g, *bb; float *ao, *bo;
    if (blockIdx.y == 0)      { ps = ps0; qs = qs0; g = g0; bb = bb0; ao = ao0; bo = bo0; }
    else if (blockIdx.y == 1) { ps = ps1; qs = qs1; g = g1; bb = bb1; ao = ao1; bo = bo1; }
    else                      { ps = ps2; qs = qs2; g = g2; bb = bb2; ao = ao2; bo = bo2; }
    int idx = blockIdx.x * 256 + threadIdx.x;
    int c = idx & 511;
    float s  = ps[idx];
    float ss = qs[idx];
    float mean = s * (1.0f / 784.0f);
    float var  = ss * (1.0f / 784.0f) - mean * mean;
    float rstd = rsqrtf(var + 1e-5f);
    float a = rstd * g[c];
    ao[idx] = a;
    bo[idx] = bb[c] - mean * a;
}

// ---------------------------------------------------------------------------
// 6) apply norm1 + quant_a: bf16 h1 -> i8 (k-128) a1
// ---------------------------------------------------------------------------
__global__ void norm_quant_i8_k(const ushort_t* __restrict__ h, const float* __restrict__ a_,
                                const float* __restrict__ b_, signed char* __restrict__ o) {
    int idx = blockIdx.x * 256 + threadIdx.x;   // over M*512/8
    int row = idx >> 6;
    int c0  = (idx & 63) * 8;
    int n   = row / OHW;
    bf16x8 v = ((const bf16x8*)h)[idx];
    const float* ap = a_ + n * CO + c0;
    const float* bp = b_ + n * CO + c0;
    unsigned lo = 0, hi = 0;
#pragma unroll
    for (int k = 0; k < 8; ++k) {
        float f = bf2f((ushort_t)v[k]) * ap[k] + bp[k];
        float kq = rintf(fminf(fmaxf(f, 0.f), 1.f) * 255.f);
        int s8 = (int)kq - 128;
        unsigned b = (unsigned)(s8 & 0xFF);
        if (k < 4) lo |= b << (8 * k);
        else       hi |= b << (8 * (k - 4));
    }
    ((uint2*)o)[idx] = make_uint2(lo, hi);
}

// ---------------------------------------------------------------------------
// 7) final: out NCHW f32 = norm2(h2) + normp(s), bf16 in, LDS transpose
// ---------------------------------------------------------------------------
__global__ void final_k(const ushort_t* __restrict__ h2, const ushort_t* __restrict__ s,
                        const float* __restrict__ a2, const float* __restrict__ b2,
                        const float* __restrict__ ap_, const float* __restrict__ bp_,
                        float* __restrict__ out) {
    __shared__ float tile[64][33];
    const int sp0 = blockIdx.x * 32;
    const int c0  = blockIdx.y * 64;
    const int n   = blockIdx.z;
    const int tx  = threadIdx.x & 31;
    const int ty  = threadIdx.x >> 5;
#pragma unroll
    for (int j = 0; j < 4; ++j) {
        int spl = ty + j * 8;
        int sp  = sp0 + spl;
        if (sp < OHW) {
            int c = c0 + tx * 2;
            size_t ix = ((size_t)n * OHW + sp) * CO + c;
            int ci = n * CO + c;
            ushort2 vh = *(const ushort2*)&h2[ix];
            ushort2 vs = *(const ushort2*)&s[ix];
            tile[tx * 2][spl] =
                bf2f(vh.x) * a2[ci] + b2[ci] + bf2f(vs.x) * ap_[ci] + bp_[ci];
            tile[tx * 2 + 1][spl] =
                bf2f(vh.y) * a2[ci + 1] + b2[ci + 1] + bf2f(vs.y) * ap_[ci + 1] + bp_[ci + 1];
        }
    }
    __syncthreads();
    const int sp = sp0 + tx;
#pragma unroll
    for (int j = 0; j < 8; ++j) {
        int cl = ty + j * 8;
        if (sp < OHW)
            out[((size_t)n * CO + c0 + cl) * OHW + sp] = tile[cl][tx];
    }
}

// ---------------------------------------------------------------------------
extern "C" void kernel_launch(void* const* d_in, const int* in_sizes, int n_in,
                              void* d_out, int out_size, void* d_ws, size_t ws_size,
                              hipStream_t stream) {
    const float* x  = (const float*)d_in[0];
    const float* w1 = (const float*)d_in[1];
    const float* g1 = (const float*)d_in[2];
    const float* b1 = (const float*)d_in[3];
    const float* w2 = (const float*)d_in[4];
    const float* g2 = (const float*)d_in[5];
    const float* b2 = (const float*)d_in[6];
    const float* wp = (const float*)d_in[7];
    const float* gp = (const float*)d_in[8];
    const float* bp = (const float*)d_in[9];
    float* out = (float*)d_out;
    char* ws = (char*)d_ws;

    signed char* xh    = (signed char*)(ws + OFF_XH);
    signed char* a1    = (signed char*)(ws + OFF_A1);
    ushort_t*    h2    = (ushort_t*)(ws + OFF_H2);
    ushort_t*    sbuf  = (ushort_t*)(ws + OFF_S);
    signed char* wt1i  = (signed char*)(ws + OFF_WT1);
    signed char* wt2i  = (signed char*)(ws + OFF_WT2);
    signed char* wtpi  = (signed char*)(ws + OFF_WTP);
    float*    a1n  = (float*)(ws + OFF_A1N);
    float*    b1n  = (float*)(ws + OFF_B1N);
    float*    a2n  = (float*)(ws + OFF_A2N);
    float*    b2n  = (float*)(ws + OFF_B2N);
    float*    apn  = (float*)(ws + OFF_APN);
    float*    bpn  = (float*)(ws + OFF_BPN);
    unsigned* mx   = (unsigned*)(ws + OFF_MX);
    signed char* zb = (signed char*)(ws + OFF_ZB);
    float*    cs   = (float*)(ws + OFF_CS);
    float*    psum1 = (float*)(ws + OFF_PSUM);
    float*    pss1  = (float*)(ws + OFF_PSUM + 65536);
    float*    psum2 = (float*)(ws + OFF_PSUM + 131072);
    float*    pss2  = (float*)(ws + OFF_PSUM + 196608);
    float*    psump = (float*)(ws + OFF_PSUM + 262144);
    float*    pssp  = (float*)(ws + OFF_PSUM + 327680);
    ushort_t* h1   = (ushort_t*)out;   // d_out doubles as conv1 bf16 scratch

    // single memset: absmax + zero page + colsum + 6 stat buffers
    hipMemsetAsync(ws + OFF_MX, 0, ZERO_LEN, stream);

    to_nhwc_i8_k<<<dim3(2, 4, NB * HIN), 256, 0, stream>>>(x, xh);
    absmax3_k<<<dim3(512, 3), 256, 0, stream>>>(w1, CO * C_IN * 9,
                                                w2, CO * CO * 9,
                                                wp, C_IN * CO, mx);
    quantw_all_k<<<dim3(14336), 256, 0, stream>>>(w1, w2, wp, mx,
                                                  wt1i, wt2i, wtpi, cs);

    // conv1 (i8 symmetric, 3x3 s2, 256->512) -> h1 bf16 (in d_out) + stats1
    conv_i8_t<C_IN, 3, 3, 2, 1, HIN, HIN, false>
        <<<dim3(196), 1024, 0, stream>>>(xh, wt1i, cs, mx + 0, S_X, h1, zb,
                                         psum1, pss1);
    statsf3_k<<<dim3(64, 1), 256, 0, stream>>>(psum1, pss1, g1, b1, a1n, b1n,
                                               psum1, pss1, g1, b1, a1n, b1n,
                                               psum1, pss1, g1, b1, a1n, b1n);
    norm_quant_i8_k<<<dim3(MTOT * CO / 8 / 256), 256, 0, stream>>>(h1, a1n, b1n, a1);

    // conv2 (i8 offset path, 3x3 s1, 512->512) -> h2 + stats2
    conv_i8_t<CO, 3, 3, 1, 1, 28, 28, true>
        <<<dim3(196), 1024, 0, stream>>>(a1, wt2i, cs, mx + 1, 1.0f, h2, zb,
                                         psum2, pss2);
    // shortcut conv (i8 symmetric, 1x1 s2, 256->512) -> s + statsp
    conv_i8_t<C_IN, 1, 1, 2, 0, HIN, HIN, false>
        <<<dim3(196), 1024, 0, stream>>>(xh, wtpi, cs, mx + 2, S_X, sbuf, zb,
                                         psump, pssp);

    statsf3_k<<<dim3(64, 2), 256, 0, stream>>>(psum2, pss2, g2, b2, a2n, b2n,
                                               psump, pssp, gp, bp, apn, bpn,
                                               psum2, pss2, g2, b2, a2n, b2n);

    final_k<<<dim3(25, 8, NB), 256, 0, stream>>>(h2, sbuf, a2n, b2n, apn, bpn, out);
}

// Round 20
// 275.693 us; speedup vs baseline: 2.6843x; 1.0072x over previous
//
#include <hip/hip_runtime.h>
#include <cstdint>
#include <cstddef>

// ---------------------------------------------------------------------------
// QBasicBlock: qconv3x3(s2) -> inorm -> quant_a -> qconv3x3(s1) -> inorm
//            + qconv1x1(s2) -> inorm  (shortcut), output sum, NCHW f32.
// R20: R19 (= R16 best baseline) + stats-finalize fused into consumers:
//      norm_quant computes the (n,c) affine inline from psum1/pss1/g1/b1;
//      final_k computes both affines inline from psum2/pss2 & psump/pssp.
//      Two statsf3 launches removed; arithmetic bit-identical.
// ---------------------------------------------------------------------------

typedef unsigned short ushort_t;
typedef __attribute__((ext_vector_type(8))) short bf16x8;
typedef __attribute__((ext_vector_type(4))) int i32x4;

// ---- problem constants ----
#define NB   32
#define C_IN 256
#define HIN  56
#define CO   512
#define OHW  784           // 28*28
#define OWD  28
#define MTOT (NB * OHW)    // 25088

#define S_X  (6.0f / 127.0f)   // fixed symmetric x-quant scale (>=6 sigma)

// ---- workspace layout (bytes) ----
constexpr size_t OFF_XH   = 0;                        // x NHWC i8
constexpr size_t OFF_A1   = OFF_XH  + 25690112;       // a1 NHWC i8
constexpr size_t OFF_H2   = OFF_A1  + 12845056;       // h2 NHWC bf16
constexpr size_t OFF_S    = OFF_H2  + 25690112;       // shortcut NHWC bf16
constexpr size_t OFF_WT1  = OFF_S   + 25690112;       // wt1 i8 [9][512][256]
constexpr size_t OFF_WT2  = OFF_WT1 + 1179648;        // wt2 i8 [9][512][512]
constexpr size_t OFF_WTP  = OFF_WT2 + 2359296;        // wtp i8 [1][512][256]
// ---- zeroed region (single memset): MX | ZB | CS | PSUM ----
constexpr size_t OFF_MX   = OFF_WTP + 131072;         // 3 uint absmax slots
constexpr size_t OFF_ZB   = OFF_MX  + 16;             // 2 KiB zero page
constexpr size_t OFF_CS   = OFF_ZB  + 2048;           // colsum f32 [9][512]
constexpr size_t OFF_PSUM = OFF_CS  + 18432;          // 6 x [32][512] f32
constexpr size_t ZERO_LEN = 16 + 2048 + 18432 + 393216;

// ---- helpers ----
__device__ __forceinline__ ushort_t f2bf(float f) {  // RNE f32->bf16
    unsigned u = __float_as_uint(f);
    u += 0x7FFFu + ((u >> 16) & 1u);
    return (ushort_t)(u >> 16);
}
__device__ __forceinline__ float bf2f(ushort_t u) {
    return __uint_as_float(((unsigned)u) << 16);
}
__device__ __forceinline__ void mkab(float s, float ss, float g, float bb,
                                     float& a, float& b) {
    float mean = s * (1.0f / 784.0f);
    float var  = ss * (1.0f / 784.0f) - mean * mean;
    float rstd = rsqrtf(var + 1e-5f);
    a = rstd * g;
    b = bb - mean * a;
}

__device__ __forceinline__ void async_copy16(const void* g, const void* l) {
    auto gp = (const __attribute__((address_space(1))) unsigned int*)(uintptr_t)g;
    auto lp = (__attribute__((address_space(3))) unsigned int*)(unsigned int)(uintptr_t)l;
    __builtin_amdgcn_global_load_lds(gp, lp, 16, 0, 0);
}

// ---------------------------------------------------------------------------
// 1) x NCHW f32 -> NHWC i8 (symmetric, fixed scale 6/127)
// ---------------------------------------------------------------------------
__global__ void to_nhwc_i8_k(const float* __restrict__ x, signed char* __restrict__ xh) {
    __shared__ float tile[64][33];
    const int wt0 = blockIdx.x * 32;
    const int ct0 = blockIdx.y * 64;
    const int nh  = blockIdx.z;
    const int n = nh / HIN, h = nh - n * HIN;
    {
        const int tx = threadIdx.x & 31;
        const int ty = threadIdx.x >> 5;
        const int w  = wt0 + tx;
#pragma unroll
        for (int j = 0; j < 8; ++j) {
            int cl = ty + j * 8;
            if (w < HIN)
                tile[cl][tx] = x[(((size_t)n * C_IN + ct0 + cl) * HIN + h) * HIN + w];
        }
    }
    __syncthreads();
    {
        const float inv = 127.0f / 6.0f;
        const int tc4 = threadIdx.x & 15;   // 16 groups of 4 channels
        const int tw  = threadIdx.x >> 4;   // 16 w slots
#pragma unroll
        for (int j = 0; j < 2; ++j) {
            int wl = tw + j * 16;
            int w  = wt0 + wl;
            if (w < HIN) {
                unsigned pk = 0;
#pragma unroll
                for (int k = 0; k < 4; ++k) {
                    float v = tile[tc4 * 4 + k][wl];
                    float q = fminf(127.f, fmaxf(-127.f, rintf(v * inv)));
                    pk |= ((unsigned)((int)q & 0xFF)) << (8 * k);
                }
                *(unsigned*)&xh[(((size_t)n * HIN + h) * HIN + w) * C_IN + ct0 + tc4 * 4] = pk;
            }
        }
    }
}

// ---------------------------------------------------------------------------
// 2) per-tensor |w| max — 3 weight tensors in one launch (float4 reads)
// ---------------------------------------------------------------------------
__global__ void absmax3_k(const float* __restrict__ w1, int n1,
                          const float* __restrict__ w2, int n2,
                          const float* __restrict__ wp, int np,
                          unsigned* out) {
    const float4* w; int nelem;
    if (blockIdx.y == 0)      { w = (const float4*)w1; nelem = n1 >> 2; }
    else if (blockIdx.y == 1) { w = (const float4*)w2; nelem = n2 >> 2; }
    else                      { w = (const float4*)wp; nelem = np >> 2; }
    int stride = gridDim.x * blockDim.x;
    float m = 0.f;
    for (int i = blockIdx.x * blockDim.x + threadIdx.x; i < nelem; i += stride) {
        float4 v = w[i];
        m = fmaxf(m, fmaxf(fmaxf(fabsf(v.x), fabsf(v.y)),
                           fmaxf(fabsf(v.z), fabsf(v.w))));
    }
#pragma unroll
    for (int off = 32; off > 0; off >>= 1)
        m = fmaxf(m, __shfl_down(m, off));
    if ((threadIdx.x & 63) == 0) atomicMax(out + blockIdx.y, __float_as_uint(m));
}

// ---------------------------------------------------------------------------
// 3) merged weight quant (all i8): [0,4608) wt1, [4608,13824) wt2 (+colsum),
//    [13824,14336) wtp.
// ---------------------------------------------------------------------------
__global__ void quantw_all_k(const float* __restrict__ w1,
                             const float* __restrict__ w2,
                             const float* __restrict__ wp,
                             const unsigned* __restrict__ mx,
                             signed char* __restrict__ wt1,
                             signed char* __restrict__ wt2,
                             signed char* __restrict__ wtp,
                             float* __restrict__ cs) {
    const int b = blockIdx.x;
    if (b < 4608) {            // w1 i8 [9][512][256]
        int idx = b * 256 + threadIdx.x;
        float scale = __uint_as_float(mx[0]) * (1.0f / 127.0f);
        float inv   = scale > 0.f ? 1.0f / scale : 0.f;
        int khw = idx / (CO * C_IN);
        int r   = idx - khw * (CO * C_IN);
        int co  = r / C_IN;
        int ci  = r - co * C_IN;
        float v  = w1[((size_t)co * C_IN + ci) * 9 + khw];
        float qv = rintf(v * inv);
        qv = fminf(127.f, fmaxf(-127.f, qv));
        wt1[idx] = (signed char)(int)qv;
    } else if (b < 13824) {    // w2 i8 [9][512][512] + colsum
        int idx = (b - 4608) * 256 + threadIdx.x;
        float scale = __uint_as_float(mx[1]) * (1.0f / 127.0f);
        float inv   = scale > 0.f ? 1.0f / scale : 0.f;
        int khw = idx / (CO * CO);
        int r   = idx - khw * (CO * CO);
        int co  = r / CO;
        int ci  = r - co * CO;
        float v  = w2[((size_t)co * CO + ci) * 9 + khw];
        float qv = rintf(v * inv);
        qv = fminf(127.f, fmaxf(-127.f, qv));
        int iq = (int)qv;
        wt2[idx] = (signed char)iq;
        int s = iq;
#pragma unroll
        for (int off = 32; off > 0; off >>= 1)
            s += __shfl_down(s, off);
        if ((threadIdx.x & 63) == 0) atomicAdd(&cs[khw * CO + co], (float)s);
    } else {                   // wp i8 [512][256]
        int idx = (b - 13824) * 256 + threadIdx.x;
        float scale = __uint_as_float(mx[2]) * (1.0f / 127.0f);
        float inv   = scale > 0.f ? 1.0f / scale : 0.f;
        int co  = idx / C_IN;
        int ci  = idx - co * C_IN;
        float v  = wp[(size_t)co * C_IN + ci];
        float qv = rintf(v * inv);
        qv = fminf(127.f, fmaxf(-127.f, qv));
        wtp[idx] = (signed char)(int)qv;
    }
}

// ---------------------------------------------------------------------------
// 4) unified INT8 implicit-GEMM conv: 256x256 tile, 196 blocks, 1024 thr
//    (16 waves, 4Mx4N, per-wave 64x64). 2 K-tiles per barrier period,
//    4-ring LDS. Conflict-free swizzle lq ^ ((row>>1)&3).
//    OFFSET=true : A = (k-128) i8 -> val = sc*dot + 128*sc*T (colsum fixup)
//    OFFSET=false: symmetric i8  -> val = sxa*sw*dot (no correction)
// ---------------------------------------------------------------------------
template <int CIN, int KH, int KW, int STRIDE, int PAD, int IH, int IW, bool OFFSET>
__launch_bounds__(1024, 4)
__global__ void conv_i8_t(const signed char* __restrict__ xin,
                          const signed char* __restrict__ wt,
                          const float* __restrict__ colsum,
                          const unsigned* __restrict__ mxw,
                          float sxa,
                          ushort_t* __restrict__ out,
                          const signed char* __restrict__ zbuf,
                          float* __restrict__ psum, float* __restrict__ pss) {
    constexpr int BK   = 64;
    constexpr int CKT  = CIN / BK;
    constexpr int KT   = KH * KW * CKT;
    constexpr int NPER = KT / 2;

    __shared__ alignas(16) signed char As[4 * 256 * BK];   // 64 KiB (4-ring)
    __shared__ alignas(16) signed char Bs[4 * 256 * BK];   // 64 KiB (4-ring)

    const int tid  = threadIdx.x;
    const int lane = tid & 63;
    const int wv   = tid >> 6;       // 0..15
    const int wm   = wv >> 2;        // 0..3
    const int wn   = wv & 3;         // 0..3
    const int lrow = lane & 15;
    const int lq   = lane >> 4;

    const int bid = blockIdx.x;
    const int xcd = bid & 7;
    const int j   = bid >> 3;
    const int wg  = (xcd < 4 ? xcd * 25 : 100 + (xcd - 4) * 24) + j;
    const int m0  = (wg >> 1) * 256;
    const int co0 = (wg & 1) * 256;

    // staging slot: row = tid>>2 (0..255), chunk = tid&3 (16B)
    const int arow = tid >> 2;
    const int ach  = tid & 3;
    int abase; unsigned amask; int bco;
    {
        int m   = m0 + arow;
        int n   = m / OHW;
        int sp  = m - n * OHW;
        int oh  = sp / OWD, ow = sp - oh * OWD;
        int ihb = oh * STRIDE - PAD, iwb = ow * STRIDE - PAD;
        int swz = (ach ^ ((arow >> 1) & 3)) * 16;   // conflict-free swizzle
        abase = (n * (IH * IW) + ihb * IW + iwb) * CIN + swz;
        unsigned mk = 0;
#pragma unroll
        for (int kh = 0; kh < KH; ++kh)
#pragma unroll
            for (int kw = 0; kw < KW; ++kw) {
                int ih = ihb + kh, iw = iwb + kw;
                if ((unsigned)ih < (unsigned)IH && (unsigned)iw < (unsigned)IW)
                    mk |= 1u << (kh * KW + kw);
            }
        amask = mk;
        bco = (co0 + arow) * CIN + swz;
    }

    auto stageA = [&](int buf, int aoff, int khw) {
        const signed char* src = ((amask >> khw) & 1)
            ? xin + (abase + aoff) : zbuf;
        async_copy16(src, (const void*)&As[buf * 16384 + wv * 1024]);
    };
    auto stageB = [&](int buf, int boff) {
        async_copy16(wt + (boff + bco), (const void*)&Bs[buf * 16384 + wv * 1024]);
    };

    i32x4 acc[4][4];
#pragma unroll
    for (int a = 0; a < 4; ++a)
#pragma unroll
        for (int b = 0; b < 4; ++b) acc[a][b] = {0, 0, 0, 0};

    // ---- prologue: tiles 0,1 -> bufs 0,1 (khw=0; ck=0,1) ----
    stageB(0, 0);  stageA(0, 0, 0);
    stageB(1, BK); stageA(1, BK, 0);
    asm volatile("s_waitcnt vmcnt(0)" ::: "memory");
    __builtin_amdgcn_s_barrier();

    int khw_n = 0, kw_n = 0, ck_n = 2;
    int aoff_n = 2 * BK;
    int boff_n = 2 * BK;

#pragma unroll 1
    for (int p = 0; p < NPER; ++p) {
        const int t0 = 2 * p;
        if (p + 1 < NPER) {
#pragma unroll
            for (int u = 0; u < 2; ++u) {
                const int buf = (t0 + 2 + u) & 3;
                stageB(buf, boff_n);
                stageA(buf, aoff_n, khw_n);
                ck_n++;
                if (ck_n == CKT) {
                    ck_n = 0; khw_n++; kw_n++;
                    if (kw_n == KW) { kw_n = 0; aoff_n += (IW - KW) * CIN + BK; }
                    else            { aoff_n += BK; }
                    boff_n += (CO - 1) * CIN + BK;
                } else {
                    aoff_n += BK; boff_n += BK;
                }
            }
        }
        __builtin_amdgcn_sched_barrier(0);

#pragma unroll
        for (int sub = 0; sub < 2; ++sub) {
            const signed char* Acur = &As[((t0 + sub) & 3) * 16384];
            const signed char* Bcur = &Bs[((t0 + sub) & 3) * 16384];
            i32x4 af[4], bfr[4];
#pragma unroll
            for (int mi = 0; mi < 4; ++mi) {
                const int row = wm * 64 + mi * 16 + lrow;
                af[mi] = *(const i32x4*)&Acur[row * BK + ((lq ^ ((row >> 1) & 3)) * 16)];
            }
#pragma unroll
            for (int ni = 0; ni < 4; ++ni) {
                const int row = wn * 64 + ni * 16 + lrow;
                bfr[ni] = *(const i32x4*)&Bcur[row * BK + ((lq ^ ((row >> 1) & 3)) * 16)];
            }
#pragma unroll
            for (int mi = 0; mi < 4; ++mi)
#pragma unroll
                for (int ni = 0; ni < 4; ++ni)
                    acc[mi][ni] = __builtin_amdgcn_mfma_i32_16x16x64_i8(
                        af[mi], bfr[ni], acc[mi][ni], 0, 0, 0);
        }

        asm volatile("s_waitcnt vmcnt(0)" ::: "memory");
        __builtin_amdgcn_sched_barrier(0);
        __builtin_amdgcn_s_barrier();
    }

    // ---- epilogue: dequant (+fixup) + bf16 store + fused stats ----
    const int mb = m0 + wm * 64 + lq * 4;
    const int cb = co0 + wn * 64 + lrow;
    const float sw = __uint_as_float(*mxw) * (1.0f / 127.0f);
    float sc, c128 = 0.f;
    if constexpr (OFFSET) { sc = sw * (1.0f / 255.0f); c128 = 128.0f * sc; }
    else                  { sc = sxa * sw; }

    float Sall[4], Sr0[4], Sr2[4], Sc0[4], Sc2[4], K0[4], K2[4], K6[4], K8[4];
    if constexpr (OFFSET) {
#pragma unroll
        for (int ni = 0; ni < 4; ++ni) {
            float cs9[9];
#pragma unroll
            for (int k = 0; k < 9; ++k) cs9[k] = colsum[k * CO + cb + ni * 16];
            Sall[ni] = cs9[0]+cs9[1]+cs9[2]+cs9[3]+cs9[4]+cs9[5]+cs9[6]+cs9[7]+cs9[8];
            Sr0[ni] = cs9[0]+cs9[1]+cs9[2];  Sr2[ni] = cs9[6]+cs9[7]+cs9[8];
            Sc0[ni] = cs9[0]+cs9[3]+cs9[6];  Sc2[ni] = cs9[2]+cs9[5]+cs9[8];
            K0[ni] = cs9[0]; K2[ni] = cs9[2]; K6[ni] = cs9[6]; K8[ni] = cs9[8];
        }
    }

    const int n0 = m0 / OHW;
    const int mS = (n0 + 1) * OHW;
    float sv[2][4], qvv[2][4];
#pragma unroll
    for (int g = 0; g < 2; ++g)
#pragma unroll
        for (int ni = 0; ni < 4; ++ni) { sv[g][ni] = 0.f; qvv[g][ni] = 0.f; }

#pragma unroll
    for (int mi = 0; mi < 4; ++mi)
#pragma unroll
        for (int r = 0; r < 4; ++r) {
            const int m  = mb + mi * 16 + r;
            const int n  = m / OHW;
            const int sp = m - n * OHW;
            const int oh = sp / OWD, ow = sp - oh * OWD;
            const int g  = (m >= mS) ? 1 : 0;
#pragma unroll
            for (int ni = 0; ni < 4; ++ni) {
                float val;
                if constexpr (OFFSET) {
                    float T = Sall[ni];
                    if (oh == 0)       T -= Sr0[ni];
                    if (oh == OWD - 1) T -= Sr2[ni];
                    if (ow == 0)       T -= Sc0[ni];
                    if (ow == OWD - 1) T -= Sc2[ni];
                    if (oh == 0 && ow == 0)             T += K0[ni];
                    if (oh == 0 && ow == OWD - 1)       T += K2[ni];
                    if (oh == OWD - 1 && ow == 0)       T += K6[ni];
                    if (oh == OWD - 1 && ow == OWD - 1) T += K8[ni];
                    val = sc * (float)acc[mi][ni][r] + c128 * T;
                } else {
                    val = sc * (float)acc[mi][ni][r];
                }
                out[(size_t)m * CO + (cb + ni * 16)] = f2bf(val);
                sv[g][ni] += val; qvv[g][ni] += val * val;
            }
        }
#pragma unroll
    for (int d = 16; d <= 32; d <<= 1)
#pragma unroll
        for (int g = 0; g < 2; ++g)
#pragma unroll
            for (int ni = 0; ni < 4; ++ni) {
                sv[g][ni]  += __shfl_xor(sv[g][ni], d);
                qvv[g][ni] += __shfl_xor(qvv[g][ni], d);
            }
    if (lq == 0) {
        const bool split = (mS < m0 + 256);
#pragma unroll
        for (int ni = 0; ni < 4; ++ni) {
            atomicAdd(&psum[n0 * CO + cb + ni * 16], sv[0][ni]);
            atomicAdd(&pss [n0 * CO + cb + ni * 16], qvv[0][ni]);
            if (split) {
                atomicAdd(&psum[(n0 + 1) * CO + cb + ni * 16], sv[1][ni]);
                atomicAdd(&pss [(n0 + 1) * CO + cb + ni * 16], qvv[1][ni]);
            }
        }
    }
}

// ---------------------------------------------------------------------------
// 5) apply norm1 + quant_a: bf16 h1 -> i8 (k-128) a1, affine computed inline
//    from psum1/pss1/g1/b1 (statsf3 fused; same f32 formula -> identical).
// ---------------------------------------------------------------------------
__global__ void norm_quant_i8_k(const ushort_t* __restrict__ h,
                                const float* __restrict__ psum,
                                const float* __restrict__ pss,
                                const float* __restrict__ g,
                                const float* __restrict__ bb,
                                signed char* __restrict__ o) {
    int idx = blockIdx.x * 256 + threadIdx.x;   // over M*512/8
    int row = idx >> 6;
    int c0  = (idx & 63) * 8;
    int n   = row / OHW;
    bf16x8 v = ((const bf16x8*)h)[idx];
    const float* ps = psum + n * CO + c0;
    const float* qs = pss  + n * CO + c0;
    unsigned lo = 0, hi = 0;
#pragma unroll
    for (int k = 0; k < 8; ++k) {
        float a, b;
        mkab(ps[k], qs[k], g[c0 + k], bb[c0 + k], a, b);
        float f = bf2f((ushort_t)v[k]) * a + b;
        float kq = rintf(fminf(fmaxf(f, 0.f), 1.f) * 255.f);
        int s8 = (int)kq - 128;
        unsigned by = (unsigned)(s8 & 0xFF);
        if (k < 4) lo |= by << (8 * k);
        else       hi |= by << (8 * (k - 4));
    }
    ((uint2*)o)[idx] = make_uint2(lo, hi);
}

// ---------------------------------------------------------------------------
// 6) final: out NCHW f32 = norm2(h2) + normp(s); affines computed inline
//    (statsf3 fused); bf16 in, LDS transpose out.
// ---------------------------------------------------------------------------
__global__ void final_k(const ushort_t* __restrict__ h2, const ushort_t* __restrict__ s,
                        const float* __restrict__ ps2, const float* __restrict__ qs2,
                        const float* __restrict__ g2, const float* __restrict__ b2,
                        const float* __restrict__ psp, const float* __restrict__ qsp,
                        const float* __restrict__ gp, const float* __restrict__ bp,
                        float* __restrict__ out) {
    __shared__ float tile[64][33];
    const int sp0 = blockIdx.x * 32;
    const int c0  = blockIdx.y * 64;
    const int n   = blockIdx.z;
    const int tx  = threadIdx.x & 31;
    const int ty  = threadIdx.x >> 5;

    // per-thread channel pair: affines computed once (outside the j loop)
    const int c  = c0 + tx * 2;
    const int ci = n * CO + c;
    float a2x, b2x, a2y, b2y, apx, bpx, apy, bpy;
    mkab(ps2[ci],     qs2[ci],     g2[c],     b2[c],     a2x, b2x);
    mkab(ps2[ci + 1], qs2[ci + 1], g2[c + 1], b2[c + 1], a2y, b2y);
    mkab(psp[ci],     qsp[ci],     gp[c],     bp[c],     apx, bpx);
    mkab(psp[ci + 1], qsp[ci + 1], gp[c + 1], bp[c + 1], apy, bpy);

#pragma unroll
    for (int j = 0; j < 4; ++j) {
        int spl = ty + j * 8;
        int sp  = sp0 + spl;
        if (sp < OHW) {
            size_t ix = ((size_t)n * OHW + sp) * CO + c;
            ushort2 vh = *(const ushort2*)&h2[ix];
            ushort2 vs = *(const ushort2*)&s[ix];
            tile[tx * 2][spl]     = bf2f(vh.x) * a2x + b2x + bf2f(vs.x) * apx + bpx;
            tile[tx * 2 + 1][spl] = bf2f(vh.y) * a2y + b2y + bf2f(vs.y) * apy + bpy;
        }
    }
    __syncthreads();
    const int sp = sp0 + tx;
#pragma unroll
    for (int j = 0; j < 8; ++j) {
        int cl = ty + j * 8;
        if (sp < OHW)
            out[((size_t)n * CO + c0 + cl) * OHW + sp] = tile[cl][tx];
    }
}

// ---------------------------------------------------------------------------
extern "C" void kernel_launch(void* const* d_in, const int* in_sizes, int n_in,
                              void* d_out, int out_size, void* d_ws, size_t ws_size,
                              hipStream_t stream) {
    const float* x  = (const float*)d_in[0];
    const float* w1 = (const float*)d_in[1];
    const float* g1 = (const float*)d_in[2];
    const float* b1 = (const float*)d_in[3];
    const float* w2 = (const float*)d_in[4];
    const float* g2 = (const float*)d_in[5];
    const float* b2 = (const float*)d_in[6];
    const float* wp = (const float*)d_in[7];
    const float* gp = (const float*)d_in[8];
    const float* bp = (const float*)d_in[9];
    float* out = (float*)d_out;
    char* ws = (char*)d_ws;

    signed char* xh    = (signed char*)(ws + OFF_XH);
    signed char* a1    = (signed char*)(ws + OFF_A1);
    ushort_t*    h2    = (ushort_t*)(ws + OFF_H2);
    ushort_t*    sbuf  = (ushort_t*)(ws + OFF_S);
    signed char* wt1i  = (signed char*)(ws + OFF_WT1);
    signed char* wt2i  = (signed char*)(ws + OFF_WT2);
    signed char* wtpi  = (signed char*)(ws + OFF_WTP);
    unsigned* mx   = (unsigned*)(ws + OFF_MX);
    signed char* zb = (signed char*)(ws + OFF_ZB);
    float*    cs   = (float*)(ws + OFF_CS);
    float*    psum1 = (float*)(ws + OFF_PSUM);
    float*    pss1  = (float*)(ws + OFF_PSUM + 65536);
    float*    psum2 = (float*)(ws + OFF_PSUM + 131072);
    float*    pss2  = (float*)(ws + OFF_PSUM + 196608);
    float*    psump = (float*)(ws + OFF_PSUM + 262144);
    float*    pssp  = (float*)(ws + OFF_PSUM + 327680);
    ushort_t* h1   = (ushort_t*)out;   // d_out doubles as conv1 bf16 scratch

    // single memset: absmax + zero page + colsum + 6 stat buffers
    hipMemsetAsync(ws + OFF_MX, 0, ZERO_LEN, stream);

    to_nhwc_i8_k<<<dim3(2, 4, NB * HIN), 256, 0, stream>>>(x, xh);
    absmax3_k<<<dim3(512, 3), 256, 0, stream>>>(w1, CO * C_IN * 9,
                                                w2, CO * CO * 9,
                                                wp, C_IN * CO, mx);
    quantw_all_k<<<dim3(14336), 256, 0, stream>>>(w1, w2, wp, mx,
                                                  wt1i, wt2i, wtpi, cs);

    // conv1 (i8 symmetric, 3x3 s2, 256->512) -> h1 bf16 (in d_out) + stats1
    conv_i8_t<C_IN, 3, 3, 2, 1, HIN, HIN, false>
        <<<dim3(196), 1024, 0, stream>>>(xh, wt1i, cs, mx + 0, S_X, h1, zb,
                                         psum1, pss1);
    // norm1 + quant_a with inline affine (stats1 fused)
    norm_quant_i8_k<<<dim3(MTOT * CO / 8 / 256), 256, 0, stream>>>(
        h1, psum1, pss1, g1, b1, a1);

    // conv2 (i8 offset path, 3x3 s1, 512->512) -> h2 + stats2
    conv_i8_t<CO, 3, 3, 1, 1, 28, 28, true>
        <<<dim3(196), 1024, 0, stream>>>(a1, wt2i, cs, mx + 1, 1.0f, h2, zb,
                                         psum2, pss2);
    // shortcut conv (i8 symmetric, 1x1 s2, 256->512) -> s + statsp
    conv_i8_t<C_IN, 1, 1, 2, 0, HIN, HIN, false>
        <<<dim3(196), 1024, 0, stream>>>(xh, wtpi, cs, mx + 2, S_X, sbuf, zb,
                                         psump, pssp);

    // final: both norms inline (stats2/statsp fused) + add + NCHW transpose
    final_k<<<dim3(25, 8, NB), 256, 0, stream>>>(h2, sbuf,
                                                 psum2, pss2, g2, b2,
                                                 psump, pssp, gp, bp, out);
}